// Round 1
// baseline (661.699 us; speedup 1.0000x reference)
//
#include <hip/hip_runtime.h>
#include <math.h>

#define DIM   768
#define LAT   20
#define NP    10
#define NB    16
#define SEQ   4096
#define SEQX  (NP + 1 + SEQ)        // 4107
#define NXROWS (NB * SEQX)          // 65712
#define NLROWS (NB * SEQ)           // 65536
#define NROWS  (NXROWS + NLROWS)    // 131248
#define EPSF  1e-5f

__device__ __forceinline__ float sigmoidf_(float z) { return 1.f / (1.f + __expf(-z)); }

// ---------------------------------------------------------------------------
// K1a: down-projection. latent[row][0..19] = quick_gelu(row @ Wd + bd)
// rows 0..NXROWS-1 come from x, the rest from local_tokens.
// Wd (768x20, 61.4KB) lives in LDS, read at wave-uniform addresses (broadcast,
// conflict-free). Each thread owns one row: 192 float4 global loads + 20 accs.
// ---------------------------------------------------------------------------
__global__ __launch_bounds__(256) void k_down(const float* __restrict__ x,
                                              const float* __restrict__ loc,
                                              const float* __restrict__ Wd,
                                              const float* __restrict__ bd,
                                              float* __restrict__ lat)
{
    __shared__ float wds[DIM * LAT];
    {
        const float4* s = (const float4*)Wd;
        float4* d = (float4*)wds;
        for (int i = threadIdx.x; i < DIM * LAT / 4; i += 256) d[i] = s[i];
    }
    __syncthreads();

    int row = blockIdx.x * 256 + threadIdx.x;
    if (row >= NROWS) return;
    const float* src = (row < NXROWS) ? (x + (size_t)row * DIM)
                                      : (loc + (size_t)(row - NXROWS) * DIM);
    float acc[LAT];
#pragma unroll
    for (int j = 0; j < LAT; j++) acc[j] = 0.f;

    for (int k = 0; k < DIM; k += 4) {
        float4 xv = *(const float4*)(src + k);
#pragma unroll
        for (int j = 0; j < LAT; j++) acc[j] += xv.x * wds[(k + 0) * LAT + j];
#pragma unroll
        for (int j = 0; j < LAT; j++) acc[j] += xv.y * wds[(k + 1) * LAT + j];
#pragma unroll
        for (int j = 0; j < LAT; j++) acc[j] += xv.z * wds[(k + 2) * LAT + j];
#pragma unroll
        for (int j = 0; j < LAT; j++) acc[j] += xv.w * wds[(k + 3) * LAT + j];
    }

    float outv[LAT];
#pragma unroll
    for (int j = 0; j < LAT; j++) {
        float z = acc[j] + bd[j];
        outv[j] = z * sigmoidf_(1.702f * z);   // quick_gelu
    }
    float4* dst = (float4*)(lat + (size_t)row * LAT);   // row*80B, 16B aligned
#pragma unroll
    for (int i = 0; i < LAT / 4; i++) dst[i] = ((float4*)outv)[i];
}

// ---------------------------------------------------------------------------
// K1b: up-projection for cls + global_img rows (in-batch idx >= NP).
// out[row] = latent[row] @ Wu + bu. Wu column-slice register-cached:
// 192 threads x float4 = all 768 cols; 64 rows per block amortize the cache.
// ---------------------------------------------------------------------------
__global__ __launch_bounds__(192) void k_up(const float* __restrict__ lat,
                                            const float* __restrict__ Wu,
                                            const float* __restrict__ bu,
                                            float* __restrict__ out)
{
    int t = threadIdx.x;
    float4 wu[LAT];
#pragma unroll
    for (int k = 0; k < LAT; k++) wu[k] = ((const float4*)Wu)[k * 192 + t];
    float4 bv = ((const float4*)bu)[t];

    int rowbase = blockIdx.x * 64;
    for (int i = 0; i < 64; i++) {
        int row = rowbase + i;
        if (row >= NXROWS) return;
        int idx = row % SEQX;
        if (idx < NP) continue;            // prompt rows written by k_prompt_out
        const float* lp = lat + (size_t)row * LAT;   // uniform -> s_loads
        float4 acc = bv;
#pragma unroll
        for (int k = 0; k < LAT; k++) {
            float l = lp[k];
            acc.x += l * wu[k].x; acc.y += l * wu[k].y;
            acc.z += l * wu[k].z; acc.w += l * wu[k].w;
        }
        ((float4*)out)[(size_t)row * 192 + t] = acc;
    }
}

// ---------------------------------------------------------------------------
// K2: per-batch tiny math: cls layernorms, prompt_importance, global_weight,
// q projections (prompts_latent @ Wgq/Wlq + b). One 64-thread block per batch.
// ---------------------------------------------------------------------------
__global__ __launch_bounds__(64) void k_small(const float* __restrict__ lat_x,
    const float* __restrict__ Wgq, const float* __restrict__ bgq,
    const float* __restrict__ Wlq, const float* __restrict__ blq,
    const float* __restrict__ lncg, const float* __restrict__ lncb,
    const float* __restrict__ Wc1, const float* __restrict__ bc1,
    const float* __restrict__ Wc2, const float* __restrict__ bc2,
    const float* __restrict__ lngg, const float* __restrict__ lngb,
    const float* __restrict__ Wg, const float* __restrict__ bg,
    float* __restrict__ qg, float* __restrict__ ql,
    float* __restrict__ imp, float* __restrict__ gw)
{
    int b = blockIdx.x, t = threadIdx.x;
    __shared__ float cls[LAT], clsln[LAT], h1[64];
    __shared__ float mu_s, rs_s;

    const float* cp = lat_x + (size_t)(b * SEQX + NP) * LAT;
    if (t < LAT) cls[t] = cp[t];
    __syncthreads();

    if (t == 0) {
        float m = 0.f;
        for (int k = 0; k < LAT; k++) m += cls[k];
        m /= LAT;
        float v = 0.f;
        for (int k = 0; k < LAT; k++) { float d = cls[k] - m; v += d * d; }
        v /= LAT;
        float rs = rsqrtf(v + EPSF);
        mu_s = m; rs_s = rs;
        // global_weight = sigmoid(LN_g(cls) @ Wg + bg)
        float s = bg[0];
        for (int k = 0; k < LAT; k++)
            s += ((cls[k] - m) * rs * lngg[k] + lngb[k]) * Wg[k];
        gw[b] = sigmoidf_(s);
    }
    __syncthreads();
    if (t < LAT) clsln[t] = (cls[t] - mu_s) * rs_s * lncg[t] + lncb[t];
    __syncthreads();

    // h1 = gelu_exact(cls_ln @ Wc1 + bc1), 64 wide
    {
        float s = bc1[t];
        for (int k = 0; k < LAT; k++) s += clsln[k] * Wc1[k * 64 + t];
        h1[t] = 0.5f * s * (1.f + erff(s * 0.70710678118f));
    }
    __syncthreads();
    if (t < NP) {
        float s = bc2[t];
        for (int i = 0; i < 64; i++) s += h1[i] * Wc2[i * NP + t];
        imp[b * NP + t] = sigmoidf_(s);
    }
    // q projections: 10 prompts x 20 dims
    for (int idx = t; idx < NP * LAT; idx += 64) {
        int p = idx / LAT, j = idx % LAT;
        const float* pl = lat_x + (size_t)(b * SEQX + p) * LAT;
        float sg = bgq[j], sl = blq[j];
        for (int k = 0; k < LAT; k++) {
            float v = pl[k];
            sg += v * Wgq[k * LAT + j];
            sl += v * Wlq[k * LAT + j];
        }
        qg[(b * NP + p) * LAT + j] = sg;
        ql[(b * NP + p) * LAT + j] = sl;
    }
}

// ---------------------------------------------------------------------------
// K3: attention context. One block per (batch, prompt, {global,local}).
// Two-pass softmax over 4096 tokens; tokens live in ws (L2-resident).
// ---------------------------------------------------------------------------
__global__ __launch_bounds__(256) void k_attn(const float* __restrict__ lat_x,
                                              const float* __restrict__ lat_l,
                                              const float* __restrict__ qg,
                                              const float* __restrict__ ql,
                                              float* __restrict__ ctxg,
                                              float* __restrict__ ctxl)
{
    int b = blockIdx.x, p = blockIdx.y, ty = blockIdx.z;
    const float* tok = (ty == 0) ? lat_x + (size_t)(b * SEQX + NP + 1) * LAT
                                 : lat_l + (size_t)b * SEQ * LAT;
    const float* q = ((ty == 0) ? qg : ql) + (size_t)(b * NP + p) * LAT;
    float* ctx = ((ty == 0) ? ctxg : ctxl) + (size_t)(b * NP + p) * LAT;

    int t = threadIdx.x;
    __shared__ float qs[LAT];
    __shared__ float red[128];
    __shared__ float Ms;
    __shared__ float tot[21];
    if (t < LAT) qs[t] = q[t];
    __syncthreads();

    const float scale = 0.22360679775f;   // 1/sqrt(20)
    float lg[16];
    float lmax = -1e30f;
    for (int i = 0; i < 16; i++) {
        const float* tk = tok + (size_t)(t + 256 * i) * LAT;
        float s = 0.f;
#pragma unroll
        for (int k = 0; k < LAT; k++) s += qs[k] * tk[k];
        s *= scale;
        lg[i] = s;
        lmax = fmaxf(lmax, s);
    }
    int wave = t >> 6, lane = t & 63;
    for (int off = 32; off; off >>= 1) lmax = fmaxf(lmax, __shfl_down(lmax, off, 64));
    if (lane == 0) red[wave] = lmax;
    __syncthreads();
    if (t == 0) Ms = fmaxf(fmaxf(red[0], red[1]), fmaxf(red[2], red[3]));
    __syncthreads();
    float M = Ms;

    float vals[21];
#pragma unroll
    for (int j = 0; j < 21; j++) vals[j] = 0.f;
    for (int i = 0; i < 16; i++) {
        float w = __expf(lg[i] - M);
        vals[20] += w;
        const float* tk = tok + (size_t)(t + 256 * i) * LAT;
#pragma unroll
        for (int k = 0; k < LAT; k++) vals[k] += w * tk[k];
    }
#pragma unroll
    for (int j = 0; j < 21; j++) {
        float v = vals[j];
        for (int off = 32; off; off >>= 1) v += __shfl_down(v, off, 64);
        vals[j] = v;
    }
    __syncthreads();
    if (lane == 0)
        for (int j = 0; j < 21; j++) red[wave * 21 + j] = vals[j];
    __syncthreads();
    if (t < 21) tot[t] = red[t] + red[21 + t] + red[42 + t] + red[63 + t];
    __syncthreads();
    if (t < LAT) ctx[t] = tot[t] / tot[20];
}

// ---------------------------------------------------------------------------
// K4: fuse gating + importance, then write the 160 prompt output rows.
// ---------------------------------------------------------------------------
__global__ __launch_bounds__(192) void k_prompt_out(const float* __restrict__ ctxg,
                                                    const float* __restrict__ ctxl,
                                                    const float* __restrict__ imp,
                                                    const float* __restrict__ gw,
                                                    const float* __restrict__ Wu,
                                                    const float* __restrict__ bu,
                                                    float* __restrict__ out)
{
    int b = blockIdx.x, p = blockIdx.y, t = threadIdx.x;
    __shared__ float enh[LAT];
    if (t < LAT) {
        float g = gw[b];
        size_t o = (size_t)(b * NP + p) * LAT + t;
        float e = g * ctxg[o] + (1.f - g) * ctxl[o];
        enh[t] = e * imp[b * NP + p];
    }
    __syncthreads();
    float4 acc = ((const float4*)bu)[t];
#pragma unroll
    for (int k = 0; k < LAT; k++) {
        float4 w = ((const float4*)Wu)[k * 192 + t];
        float e = enh[k];
        acc.x += e * w.x; acc.y += e * w.y; acc.z += e * w.z; acc.w += e * w.w;
    }
    ((float4*)out)[(size_t)(b * SEQX + p) * 192 + t] = acc;
}

// ---------------------------------------------------------------------------
extern "C" void kernel_launch(void* const* d_in, const int* in_sizes, int n_in,
                              void* d_out, int out_size, void* d_ws, size_t ws_size,
                              hipStream_t stream)
{
    const float* x    = (const float*)d_in[0];
    const float* loc  = (const float*)d_in[1];
    const float* Wd   = (const float*)d_in[2];
    const float* bd   = (const float*)d_in[3];
    const float* Wu   = (const float*)d_in[4];
    const float* bu   = (const float*)d_in[5];
    const float* Wgq  = (const float*)d_in[6];
    const float* bgq  = (const float*)d_in[7];
    const float* Wlq  = (const float*)d_in[8];
    const float* blq  = (const float*)d_in[9];
    const float* lncg = (const float*)d_in[10];
    const float* lncb = (const float*)d_in[11];
    const float* Wc1  = (const float*)d_in[12];
    const float* bc1  = (const float*)d_in[13];
    const float* Wc2  = (const float*)d_in[14];
    const float* bc2  = (const float*)d_in[15];
    const float* lngg = (const float*)d_in[16];
    const float* lngb = (const float*)d_in[17];
    const float* Wg   = (const float*)d_in[18];
    const float* bg   = (const float*)d_in[19];
    float* out = (float*)d_out;

    float* ws   = (float*)d_ws;
    float* lat_x = ws;                                   // NXROWS*LAT
    float* lat_l = lat_x + (size_t)NXROWS * LAT;         // NLROWS*LAT (contiguous after lat_x)
    float* qg    = lat_l + (size_t)NLROWS * LAT;
    float* ql    = qg + NB * NP * LAT;
    float* ctxg  = ql + NB * NP * LAT;
    float* ctxl  = ctxg + NB * NP * LAT;
    float* impw  = ctxl + NB * NP * LAT;
    float* gww   = impw + NB * NP;
    // total ws use: ~2.64M floats = 10.6 MB

    k_down<<<(NROWS + 255) / 256, 256, 0, stream>>>(x, loc, Wd, bd, lat_x);
    k_up<<<(NXROWS + 63) / 64, 192, 0, stream>>>(lat_x, Wu, bu, out);
    k_small<<<NB, 64, 0, stream>>>(lat_x, Wgq, bgq, Wlq, blq, lncg, lncb,
                                   Wc1, bc1, Wc2, bc2, lngg, lngb, Wg, bg,
                                   qg, ql, impw, gww);
    k_attn<<<dim3(NB, NP, 2), 256, 0, stream>>>(lat_x, lat_l, qg, ql, ctxg, ctxl);
    k_prompt_out<<<dim3(NB, NP), 192, 0, stream>>>(ctxg, ctxl, impw, gww, Wu, bu, out);
}

// Round 2
// 640.856 us; speedup vs baseline: 1.0325x; 1.0325x over previous
//
#include <hip/hip_runtime.h>
#include <math.h>

#define DIM   768
#define LAT   20
#define NP    10
#define NB    16
#define SEQ   4096
#define SEQX  (NP + 1 + SEQ)        // 4107
#define NXROWS (NB * SEQX)          // 65712
#define NLROWS (NB * SEQ)           // 65536
#define NROWS  (NXROWS + NLROWS)    // 131248
#define EPSF  1e-5f

typedef __attribute__((ext_vector_type(8))) short  v8s;
typedef __attribute__((ext_vector_type(4))) float  v4f;
typedef __attribute__((ext_vector_type(4))) unsigned short u16x4;
typedef __attribute__((ext_vector_type(8))) unsigned short u16x8;

__device__ __forceinline__ float sigmoidf_(float z) { return 1.f / (1.f + __expf(-z)); }

__device__ __forceinline__ unsigned short bf16u(float v) {
    unsigned u = __builtin_bit_cast(unsigned, v);
    unsigned r = u + 0x7fffu + ((u >> 16) & 1u);   // RNE
    return (unsigned short)(r >> 16);
}

// ---------------------------------------------------------------------------
// K1a: down-projection via bf16 MFMA.  lat[row][j] = quick_gelu(row @ Wd + bd)
// Per block: 64 rows (4 waves x 16-row m-tile), N=20 as two 16-wide n-tiles,
// K=768 in six 128-chunks, double-buffered.  LDS: W-frags 48KB + 2x16KB x-frags.
// Fragment layouts (16x16x32 bf16): A[m=l&15][k=(l>>4)*8+e], B[k][n=l&15],
// C/D col=l&15, row=(l>>4)*4+reg  [m89-verified].
// ---------------------------------------------------------------------------
#define WF_US   24576                  // 24 fs * 2 nt * 64 lanes * 8 ushort
#define XBUF_US 8192                   // 4 s * 4 t * 64 lanes * 8 ushort
__global__ __launch_bounds__(256, 2) void k_down(const float* __restrict__ x,
                                                 const float* __restrict__ loc,
                                                 const float* __restrict__ Wd,
                                                 const float* __restrict__ bd,
                                                 float* __restrict__ lat)
{
    __shared__ __align__(16) unsigned short lds[WF_US + 2 * XBUF_US];
    const int tid = threadIdx.x;
    const int rowbase = blockIdx.x * 64;

    // ---- build W fragments (once per block) ----
    for (int slot = tid; slot < 3072; slot += 256) {
        int fs = slot >> 7;            // 0..23  (k-step of 32)
        int rem = slot & 127;
        int nt = rem >> 6, l = rem & 63;
        int n = nt * 16 + (l & 15);
        int q = l >> 4;
        u16x8 w;
#pragma unroll
        for (int e = 0; e < 8; e++) {
            int k = fs * 32 + q * 8 + e;
            float v = (n < LAT) ? Wd[k * LAT + n] : 0.f;
            w[e] = bf16u(v);
        }
        *(u16x8*)&lds[((fs * 2 + nt) * 64 + l) * 8] = w;
    }

    // ---- staging lambda: chunk c (128 k's) -> bf16 fragments in buffer b ----
    auto stage = [&](int c, int b) {
        const int base = WF_US + b * XBUF_US;
#pragma unroll
        for (int i = 0; i < 8; i++) {
            int g = tid + 256 * i;         // 0..2047 float4-slots
            int row_l = g >> 5, fq = g & 31;
            int kc = fq << 2;              // k within chunk, 0..124
            int row = rowbase + row_l;
            float4 f = make_float4(0.f, 0.f, 0.f, 0.f);
            if (row < NROWS) {
                const float* src = (row < NXROWS) ? x + (size_t)row * DIM
                                                  : loc + (size_t)(row - NXROWS) * DIM;
                f = *(const float4*)(src + c * 128 + kc);
            }
            int s = kc >> 5, q = (kc >> 3) & 3, e = kc & 7;
            int t = row_l >> 4, m = row_l & 15;
            int lane = q * 16 + m;
            u16x4 u = { bf16u(f.x), bf16u(f.y), bf16u(f.z), bf16u(f.w) };
            *(u16x4*)&lds[base + ((s * 4 + t) * 64 + lane) * 8 + e] = u;
        }
    };

    stage(0, 0);
    __syncthreads();

    const int t = tid >> 6, l = tid & 63;
    v4f acc0 = {0.f, 0.f, 0.f, 0.f}, acc1 = {0.f, 0.f, 0.f, 0.f};

    for (int c = 0; c < 6; c++) {
        if (c < 5) stage(c + 1, (c + 1) & 1);
        const int base = WF_US + (c & 1) * XBUF_US;
#pragma unroll
        for (int s = 0; s < 4; s++) {
            v8s a  = *(const v8s*)&lds[base + ((s * 4 + t) * 64 + l) * 8];
            int fs = c * 4 + s;
            v8s b0 = *(const v8s*)&lds[((fs * 2 + 0) * 64 + l) * 8];
            v8s b1 = *(const v8s*)&lds[((fs * 2 + 1) * 64 + l) * 8];
            acc0 = __builtin_amdgcn_mfma_f32_16x16x32_bf16(a, b0, acc0, 0, 0, 0);
            acc1 = __builtin_amdgcn_mfma_f32_16x16x32_bf16(a, b1, acc1, 0, 0, 0);
        }
        __syncthreads();
    }

    // ---- epilogue: bias + quick_gelu, scattered store (10.5 MB total) ----
    int col = l & 15, half = l >> 4;
#pragma unroll
    for (int nt = 0; nt < 2; nt++) {
        int j = nt * 16 + col;
        if (j >= LAT) continue;
        float bdj = bd[j];
        v4f A = nt ? acc1 : acc0;
#pragma unroll
        for (int r = 0; r < 4; r++) {
            int rowg = rowbase + t * 16 + half * 4 + r;
            if (rowg < NROWS) {
                float z = A[r] + bdj;
                lat[(size_t)rowg * LAT + j] = z * sigmoidf_(1.702f * z);
            }
        }
    }
}

// ---------------------------------------------------------------------------
// K1b: up-projection for cls + global_img rows.  Wu column-slice in VGPRs
// (192 threads x float4 = 768 cols); latent rows staged via LDS (coalesced),
// consumed as uniform broadcasts.  64 rows per block.
// ---------------------------------------------------------------------------
__global__ __launch_bounds__(192, 3) void k_up(const float* __restrict__ lat,
                                               const float* __restrict__ Wu,
                                               const float* __restrict__ bu,
                                               float* __restrict__ out)
{
    int t = threadIdx.x;
    float4 wu[LAT];
#pragma unroll
    for (int k = 0; k < LAT; k++) wu[k] = ((const float4*)Wu)[k * 192 + t];
    float4 bv = ((const float4*)bu)[t];

    __shared__ float latile[64 * LAT];
    int rowbase = blockIdx.x * 64;
    {   // coalesced tile load: 320 float4 (reads past lat_x end land in lat_l, harmless)
        const float4* src = (const float4*)(lat + (size_t)rowbase * LAT);
        for (int idx = t; idx < 320; idx += 192) ((float4*)latile)[idx] = src[idx];
    }
    __syncthreads();

    int idx0 = rowbase % SEQX;
    for (int i = 0; i < 64; i++) {
        int row = rowbase + i;
        if (row >= NXROWS) break;
        int idx = idx0 + i;
        if (idx >= SEQX) idx -= SEQX;
        if (idx < NP) continue;            // prompt rows written by k_prompt_out
        const float* lp = latile + i * LAT;
        float4 acc = bv;
#pragma unroll
        for (int k = 0; k < LAT; k++) {
            float v = lp[k];
            acc.x += v * wu[k].x; acc.y += v * wu[k].y;
            acc.z += v * wu[k].z; acc.w += v * wu[k].w;
        }
        ((float4*)out)[(size_t)row * 192 + t] = acc;
    }
}

// ---------------------------------------------------------------------------
// K2: per-batch tiny math (unchanged from R1 — proven correct, ~µs scale)
// ---------------------------------------------------------------------------
__global__ __launch_bounds__(64) void k_small(const float* __restrict__ lat_x,
    const float* __restrict__ Wgq, const float* __restrict__ bgq,
    const float* __restrict__ Wlq, const float* __restrict__ blq,
    const float* __restrict__ lncg, const float* __restrict__ lncb,
    const float* __restrict__ Wc1, const float* __restrict__ bc1,
    const float* __restrict__ Wc2, const float* __restrict__ bc2,
    const float* __restrict__ lngg, const float* __restrict__ lngb,
    const float* __restrict__ Wg, const float* __restrict__ bg,
    float* __restrict__ qg, float* __restrict__ ql,
    float* __restrict__ imp, float* __restrict__ gw)
{
    int b = blockIdx.x, t = threadIdx.x;
    __shared__ float cls[LAT], clsln[LAT], h1[64];
    __shared__ float mu_s, rs_s;

    const float* cp = lat_x + (size_t)(b * SEQX + NP) * LAT;
    if (t < LAT) cls[t] = cp[t];
    __syncthreads();

    if (t == 0) {
        float m = 0.f;
        for (int k = 0; k < LAT; k++) m += cls[k];
        m /= LAT;
        float v = 0.f;
        for (int k = 0; k < LAT; k++) { float d = cls[k] - m; v += d * d; }
        v /= LAT;
        float rs = rsqrtf(v + EPSF);
        mu_s = m; rs_s = rs;
        float s = bg[0];
        for (int k = 0; k < LAT; k++)
            s += ((cls[k] - m) * rs * lngg[k] + lngb[k]) * Wg[k];
        gw[b] = sigmoidf_(s);
    }
    __syncthreads();
    if (t < LAT) clsln[t] = (cls[t] - mu_s) * rs_s * lncg[t] + lncb[t];
    __syncthreads();

    {
        float s = bc1[t];
        for (int k = 0; k < LAT; k++) s += clsln[k] * Wc1[k * 64 + t];
        h1[t] = 0.5f * s * (1.f + erff(s * 0.70710678118f));
    }
    __syncthreads();
    if (t < NP) {
        float s = bc2[t];
        for (int i = 0; i < 64; i++) s += h1[i] * Wc2[i * NP + t];
        imp[b * NP + t] = sigmoidf_(s);
    }
    for (int idx = t; idx < NP * LAT; idx += 64) {
        int p = idx / LAT, j = idx % LAT;
        const float* pl = lat_x + (size_t)(b * SEQX + p) * LAT;
        float sg = bgq[j], sl = blq[j];
        for (int k = 0; k < LAT; k++) {
            float v = pl[k];
            sg += v * Wgq[k * LAT + j];
            sl += v * Wlq[k * LAT + j];
        }
        qg[(b * NP + p) * LAT + j] = sg;
        ql[(b * NP + p) * LAT + j] = sl;
    }
}

// ---------------------------------------------------------------------------
// K3: attention context (unchanged from R1)
// ---------------------------------------------------------------------------
__global__ __launch_bounds__(256) void k_attn(const float* __restrict__ lat_x,
                                              const float* __restrict__ lat_l,
                                              const float* __restrict__ qg,
                                              const float* __restrict__ ql,
                                              float* __restrict__ ctxg,
                                              float* __restrict__ ctxl)
{
    int b = blockIdx.x, p = blockIdx.y, ty = blockIdx.z;
    const float* tok = (ty == 0) ? lat_x + (size_t)(b * SEQX + NP + 1) * LAT
                                 : lat_l + (size_t)b * SEQ * LAT;
    const float* q = ((ty == 0) ? qg : ql) + (size_t)(b * NP + p) * LAT;
    float* ctx = ((ty == 0) ? ctxg : ctxl) + (size_t)(b * NP + p) * LAT;

    int t = threadIdx.x;
    __shared__ float qs[LAT];
    __shared__ float red[128];
    __shared__ float Ms;
    __shared__ float tot[21];
    if (t < LAT) qs[t] = q[t];
    __syncthreads();

    const float scale = 0.22360679775f;   // 1/sqrt(20)
    float lg[16];
    float lmax = -1e30f;
    for (int i = 0; i < 16; i++) {
        const float* tk = tok + (size_t)(t + 256 * i) * LAT;
        float s = 0.f;
#pragma unroll
        for (int k = 0; k < LAT; k++) s += qs[k] * tk[k];
        s *= scale;
        lg[i] = s;
        lmax = fmaxf(lmax, s);
    }
    int wave = t >> 6, lane = t & 63;
    for (int off = 32; off; off >>= 1) lmax = fmaxf(lmax, __shfl_down(lmax, off, 64));
    if (lane == 0) red[wave] = lmax;
    __syncthreads();
    if (t == 0) Ms = fmaxf(fmaxf(red[0], red[1]), fmaxf(red[2], red[3]));
    __syncthreads();
    float M = Ms;

    float vals[21];
#pragma unroll
    for (int j = 0; j < 21; j++) vals[j] = 0.f;
    for (int i = 0; i < 16; i++) {
        float w = __expf(lg[i] - M);
        vals[20] += w;
        const float* tk = tok + (size_t)(t + 256 * i) * LAT;
#pragma unroll
        for (int k = 0; k < LAT; k++) vals[k] += w * tk[k];
    }
#pragma unroll
    for (int j = 0; j < 21; j++) {
        float v = vals[j];
        for (int off = 32; off; off >>= 1) v += __shfl_down(v, off, 64);
        vals[j] = v;
    }
    __syncthreads();
    if (lane == 0)
        for (int j = 0; j < 21; j++) red[wave * 21 + j] = vals[j];
    __syncthreads();
    if (t < 21) tot[t] = red[t] + red[21 + t] + red[42 + t] + red[63 + t];
    __syncthreads();
    if (t < LAT) ctx[t] = tot[t] / tot[20];
}

// ---------------------------------------------------------------------------
// K4: prompt-row outputs (unchanged from R1)
// ---------------------------------------------------------------------------
__global__ __launch_bounds__(192) void k_prompt_out(const float* __restrict__ ctxg,
                                                    const float* __restrict__ ctxl,
                                                    const float* __restrict__ imp,
                                                    const float* __restrict__ gw,
                                                    const float* __restrict__ Wu,
                                                    const float* __restrict__ bu,
                                                    float* __restrict__ out)
{
    int b = blockIdx.x, p = blockIdx.y, t = threadIdx.x;
    __shared__ float enh[LAT];
    if (t < LAT) {
        float g = gw[b];
        size_t o = (size_t)(b * NP + p) * LAT + t;
        float e = g * ctxg[o] + (1.f - g) * ctxl[o];
        enh[t] = e * imp[b * NP + p];
    }
    __syncthreads();
    float4 acc = ((const float4*)bu)[t];
#pragma unroll
    for (int k = 0; k < LAT; k++) {
        float4 w = ((const float4*)Wu)[k * 192 + t];
        float e = enh[k];
        acc.x += e * w.x; acc.y += e * w.y; acc.z += e * w.z; acc.w += e * w.w;
    }
    ((float4*)out)[(size_t)(b * SEQX + p) * 192 + t] = acc;
}

// ---------------------------------------------------------------------------
extern "C" void kernel_launch(void* const* d_in, const int* in_sizes, int n_in,
                              void* d_out, int out_size, void* d_ws, size_t ws_size,
                              hipStream_t stream)
{
    const float* x    = (const float*)d_in[0];
    const float* loc  = (const float*)d_in[1];
    const float* Wd   = (const float*)d_in[2];
    const float* bd   = (const float*)d_in[3];
    const float* Wu   = (const float*)d_in[4];
    const float* bu   = (const float*)d_in[5];
    const float* Wgq  = (const float*)d_in[6];
    const float* bgq  = (const float*)d_in[7];
    const float* Wlq  = (const float*)d_in[8];
    const float* blq  = (const float*)d_in[9];
    const float* lncg = (const float*)d_in[10];
    const float* lncb = (const float*)d_in[11];
    const float* Wc1  = (const float*)d_in[12];
    const float* bc1  = (const float*)d_in[13];
    const float* Wc2  = (const float*)d_in[14];
    const float* bc2  = (const float*)d_in[15];
    const float* lngg = (const float*)d_in[16];
    const float* lngb = (const float*)d_in[17];
    const float* Wg   = (const float*)d_in[18];
    const float* bg   = (const float*)d_in[19];
    float* out = (float*)d_out;

    float* ws   = (float*)d_ws;
    float* lat_x = ws;                                   // NXROWS*LAT
    float* lat_l = lat_x + (size_t)NXROWS * LAT;         // NLROWS*LAT (contiguous)
    float* qg    = lat_l + (size_t)NLROWS * LAT;
    float* ql    = qg + NB * NP * LAT;
    float* ctxg  = ql + NB * NP * LAT;
    float* ctxl  = ctxg + NB * NP * LAT;
    float* impw  = ctxl + NB * NP * LAT;
    float* gww   = impw + NB * NP;

    k_down<<<(NROWS + 63) / 64, 256, 0, stream>>>(x, loc, Wd, bd, lat_x);
    k_up<<<(NXROWS + 63) / 64, 192, 0, stream>>>(lat_x, Wu, bu, out);
    k_small<<<NB, 64, 0, stream>>>(lat_x, Wgq, bgq, Wlq, blq, lncg, lncb,
                                   Wc1, bc1, Wc2, bc2, lngg, lngb, Wg, bg,
                                   qg, ql, impw, gww);
    k_attn<<<dim3(NB, NP, 2), 256, 0, stream>>>(lat_x, lat_l, qg, ql, ctxg, ctxl);
    k_prompt_out<<<dim3(NB, NP), 192, 0, stream>>>(ctxg, ctxl, impw, gww, Wu, bu, out);
}